// Round 1
// baseline (410.370 us; speedup 1.0000x reference)
//
#include <hip/hip_runtime.h>
#include <stdint.h>

typedef unsigned short u16;
typedef __attribute__((ext_vector_type(8))) short s16x8;   // 8 bf16 in 4 VGPRs
typedef __attribute__((ext_vector_type(4))) float f32x4;   // MFMA accumulator

#define NEXP 8
#define HD 1024
#define DFF 4096
#define BM 128
#define BN 128
#define BK 32
#define BKP 40   // padded LDS-B row stride (bf16 elems): 80B rows keep 16B align, spread banks

__device__ __forceinline__ u16 f2bf(float f) {
  union { float f; unsigned u; } c; c.f = f;
  unsigned r = c.u + 0x7fffu + ((c.u >> 16) & 1u);   // RNE
  return (u16)(r >> 16);
}

__device__ __forceinline__ void gload_lds16(const void* g, void* l) {
  // dest = wave-uniform LDS base + lane*16 (HW behavior); pass uniform base.
  __builtin_amdgcn_global_load_lds(
      (const __attribute__((address_space(1))) unsigned int*)(uintptr_t)g,
      (__attribute__((address_space(3))) unsigned int*)(unsigned)(uintptr_t)l,
      16, 0, 0);
}

__global__ __launch_bounds__(64) void zero_k(int* counts) {
  if (threadIdx.x < NEXP) counts[threadIdx.x] = 0;
}

__global__ __launch_bounds__(64) void router_k(const float* __restrict__ x,
    const float* __restrict__ Wr, const float* __restrict__ br,
    int* __restrict__ counts, int* __restrict__ tok_exp, float* __restrict__ tok_gate) {
  const int t = blockIdx.x, l = threadIdx.x;
  const float* xr = x + (size_t)t * HD;
  float acc[NEXP];
#pragma unroll
  for (int j = 0; j < NEXP; ++j) acc[j] = 0.f;
  for (int h = l; h < HD; h += 64) {
    float xv = xr[h];
    const float4* w4 = (const float4*)(Wr + (size_t)h * NEXP);
    float4 a = w4[0], b = w4[1];
    acc[0] += xv * a.x; acc[1] += xv * a.y; acc[2] += xv * a.z; acc[3] += xv * a.w;
    acc[4] += xv * b.x; acc[5] += xv * b.y; acc[6] += xv * b.z; acc[7] += xv * b.w;
  }
#pragma unroll
  for (int j = 0; j < NEXP; ++j)
#pragma unroll
    for (int off = 32; off > 0; off >>= 1) acc[j] += __shfl_xor(acc[j], off);
  if (l == 0) {
    float lg[NEXP];
    float best = acc[0] + br[0]; int bi = 0;
    lg[0] = best;
#pragma unroll
    for (int j = 1; j < NEXP; ++j) {
      lg[j] = acc[j] + br[j];
      if (lg[j] > best) { best = lg[j]; bi = j; }   // strict > => first-index tie-break
    }
    float s = 0.f;
#pragma unroll
    for (int j = 0; j < NEXP; ++j) s += expf(lg[j] - best);
    tok_exp[t] = bi;
    tok_gate[t] = 1.0f / s;     // softmax max prob = exp(0)/sum
    atomicAdd(&counts[bi], 1);
  }
}

__global__ __launch_bounds__(64) void scan_k(const int* __restrict__ counts,
                                             int* __restrict__ seg, int* __restrict__ cursor) {
  if (threadIdx.x == 0) {
    int s = 0;
#pragma unroll
    for (int e = 0; e < NEXP; ++e) { seg[e] = s; cursor[e] = s; s += counts[e]; }
    seg[NEXP] = s;
  }
}

__global__ __launch_bounds__(64) void gather_k(const float* __restrict__ x,
    const int* __restrict__ tok_exp, const float* __restrict__ tok_gate,
    int* __restrict__ cursor, int* __restrict__ perm, float* __restrict__ gatep,
    u16* __restrict__ Xg) {
  const int t = blockIdx.x, l = threadIdx.x;
  int pos = 0;
  if (l == 0) {
    int e = tok_exp[t];
    pos = atomicAdd(&cursor[e], 1);
    perm[pos] = t;
    gatep[pos] = tok_gate[t];
  }
  pos = __shfl(pos, 0);
  const float4* xr = (const float4*)(x + (size_t)t * HD);
  ushort4* dst = (ushort4*)(Xg + (size_t)pos * HD);
#pragma unroll
  for (int i = 0; i < HD / 4 / 64; ++i) {
    float4 v = xr[l + i * 64];
    ushort4 o;
    o.x = f2bf(v.x); o.y = f2bf(v.y); o.z = f2bf(v.z); o.w = f2bf(v.w);
    dst[l + i * 64] = o;
  }
}

// Grouped GEMM over permuted rows. A: [T][KD] bf16 row-major. W: [E][KD][ND] f32.
// EPI 0: H1out = bf16(relu(acc + bias)).  EPI 1: Yout[perm[row]] = (acc + bias) * gatep[row].
template <int KD, int ND, int EPI>
__global__ __launch_bounds__(256) void ffn_gemm(
    const u16* __restrict__ A, const float* __restrict__ W,
    const float* __restrict__ bias, const int* __restrict__ seg,
    u16* __restrict__ H1out, float* __restrict__ Yout,
    const int* __restrict__ perm, const float* __restrict__ gatep) {
  const int e = blockIdx.z;
  const int s0 = seg[e];
  const int cnt = seg[e + 1] - s0;
  const int m0 = blockIdx.y * BM;
  if (m0 >= cnt) return;
  const int n0 = blockIdx.x * BN;

  __shared__ __align__(16) u16 As[BM * BK];     // [128][32] linear
  __shared__ __align__(16) u16 Bs[BN * BKP];    // [128 n][40] transposed tile

  const int t = threadIdx.x;
  const int l = t & 63, w = t >> 6;
  const int wr = w >> 1, wc = w & 1;            // wave -> 64x64 quadrant

  const f32x4 fzero = {0.f, 0.f, 0.f, 0.f};
  f32x4 acc[4][4];
#pragma unroll
  for (int i = 0; i < 4; ++i)
#pragma unroll
    for (int j = 0; j < 4; ++j) acc[i][j] = fzero;

  // A-staging: 2 chunks x 256 threads x 16B = 8KB tile; row = idx8/4, k = (idx8%4)*8
  const u16* asrc[2];
#pragma unroll
  for (int i = 0; i < 2; ++i) {
    int idx8 = i * 256 + t;
    int row = idx8 >> 2;
    int kc = (idx8 & 3) * 8;
    int rg = m0 + row;
    if (rg >= cnt) rg = cnt - 1;                // clamp to valid row; stores are guarded
    asrc[i] = A + (size_t)(s0 + rg) * KD + kc;
  }
  // B-staging: micro 8k x 2n per thread: 8 float2 loads (coalesced), convert, 2 ds_write_b128
  const int nb = t & 63;
  const int kb = (t >> 6) * 8;
  const float* wbase = W + ((size_t)e * KD) * ND + n0;

  for (int k0 = 0; k0 < KD; k0 += BK) {
    __syncthreads();
#pragma unroll
    for (int i = 0; i < 2; ++i)
      gload_lds16(asrc[i] + k0, &As[i * 2048 + w * 512]);
    const float* bp = wbase + (size_t)(k0 + kb) * ND + nb * 2;
    float2 bv[8];
#pragma unroll
    for (int j = 0; j < 8; ++j) bv[j] = *(const float2*)(bp + (size_t)j * ND);
    s16x8 p0, p1;
#pragma unroll
    for (int j = 0; j < 8; ++j) {
      p0[j] = (short)f2bf(bv[j].x);
      p1[j] = (short)f2bf(bv[j].y);
    }
    *(s16x8*)&Bs[(nb * 2 + 0) * BKP + kb] = p0;
    *(s16x8*)&Bs[(nb * 2 + 1) * BKP + kb] = p1;
    __syncthreads();

    s16x8 af[4], bfr[4];
#pragma unroll
    for (int mi = 0; mi < 4; ++mi)
      af[mi] = *(const s16x8*)&As[(wr * 64 + mi * 16 + (l & 15)) * BK + (l >> 4) * 8];
#pragma unroll
    for (int ni = 0; ni < 4; ++ni)
      bfr[ni] = *(const s16x8*)&Bs[(wc * 64 + ni * 16 + (l & 15)) * BKP + (l >> 4) * 8];
#pragma unroll
    for (int mi = 0; mi < 4; ++mi)
#pragma unroll
      for (int ni = 0; ni < 4; ++ni)
        acc[mi][ni] = __builtin_amdgcn_mfma_f32_16x16x32_bf16(af[mi], bfr[ni], acc[mi][ni], 0, 0, 0);
  }

  // epilogue: C/D frag map col=lane&15, row=(lane>>4)*4+reg  [verified m89/m91]
  const int lr = (l >> 4) * 4;
  const int lc = l & 15;
  float bv2[4];
#pragma unroll
  for (int ni = 0; ni < 4; ++ni)
    bv2[ni] = bias[(size_t)e * ND + n0 + wc * 64 + ni * 16 + lc];

  if constexpr (EPI == 0) {
#pragma unroll
    for (int mi = 0; mi < 4; ++mi) {
#pragma unroll
      for (int r = 0; r < 4; ++r) {
        int row = m0 + wr * 64 + mi * 16 + lr + r;
        if (row < cnt) {
          u16* hrow = H1out + (size_t)(s0 + row) * ND + n0 + wc * 64;
#pragma unroll
          for (int ni = 0; ni < 4; ++ni) {
            float v = acc[mi][ni][r] + bv2[ni];
            v = v > 0.f ? v : 0.f;
            hrow[ni * 16 + lc] = f2bf(v);
          }
        }
      }
    }
  } else {
#pragma unroll
    for (int mi = 0; mi < 4; ++mi) {
#pragma unroll
      for (int r = 0; r < 4; ++r) {
        int row = m0 + wr * 64 + mi * 16 + lr + r;
        if (row < cnt) {
          int tok = perm[s0 + row];
          float g = gatep[s0 + row];
          float* orow = Yout + (size_t)tok * ND + n0 + wc * 64;
#pragma unroll
          for (int ni = 0; ni < 4; ++ni)
            orow[ni * 16 + lc] = (acc[mi][ni][r] + bv2[ni]) * g;
        }
      }
    }
  }
}

extern "C" void kernel_launch(void* const* d_in, const int* in_sizes, int n_in,
                              void* d_out, int out_size, void* d_ws, size_t ws_size,
                              hipStream_t stream) {
  const float* x  = (const float*)d_in[0];
  const float* Wr = (const float*)d_in[1];
  const float* br = (const float*)d_in[2];
  const float* W1 = (const float*)d_in[3];
  const float* b1 = (const float*)d_in[4];
  const float* W2 = (const float*)d_in[5];
  const float* b2 = (const float*)d_in[6];
  float* out = (float*)d_out;

  const int T = in_sizes[0] / HD;   // 4096 tokens
  char* ws = (char*)d_ws;
  int*   counts   = (int*)(ws + 0);
  int*   cursor   = (int*)(ws + 64);
  int*   seg      = (int*)(ws + 128);
  int*   tok_exp  = (int*)(ws + 256);
  float* tok_gate = (float*)(ws + 256 + 4 * (size_t)T);
  int*   perm     = (int*)(ws + 256 + 8 * (size_t)T);
  float* gatep    = (float*)(ws + 256 + 12 * (size_t)T);
  u16*   Xg       = (u16*)(ws + 256 + 16 * (size_t)T);                       // T*HD bf16
  u16*   H1       = (u16*)(ws + 256 + 16 * (size_t)T + 2 * (size_t)T * HD);  // T*DFF bf16

  hipLaunchKernelGGL(zero_k, dim3(1), dim3(64), 0, stream, counts);
  hipLaunchKernelGGL(router_k, dim3(T), dim3(64), 0, stream, x, Wr, br, counts, tok_exp, tok_gate);
  hipLaunchKernelGGL(scan_k, dim3(1), dim3(64), 0, stream, counts, seg, cursor);
  hipLaunchKernelGGL(gather_k, dim3(T), dim3(64), 0, stream, x, tok_exp, tok_gate, cursor, perm, gatep, Xg);
  const int mt = (T + BM - 1) / BM;
  hipLaunchKernelGGL((ffn_gemm<HD, DFF, 0>), dim3(DFF / BN, mt, NEXP), dim3(256), 0, stream,
                     Xg, W1, b1, seg, H1, nullptr, nullptr, nullptr);
  hipLaunchKernelGGL((ffn_gemm<DFF, HD, 1>), dim3(HD / BN, mt, NEXP), dim3(256), 0, stream,
                     H1, W2, b2, seg, nullptr, out, perm, gatep);
}

// Round 2
// 334.534 us; speedup vs baseline: 1.2267x; 1.2267x over previous
//
#include <hip/hip_runtime.h>
#include <stdint.h>

typedef unsigned short u16;
typedef __attribute__((ext_vector_type(8))) short s16x8;   // 8 bf16 in 4 VGPRs
typedef __attribute__((ext_vector_type(4))) float f32x4;   // MFMA accumulator

#define NEXP 8
#define HD 1024
#define DFF 4096
#define BM 128
#define BN 128
#define BK 32
#define BKP 40   // padded LDS-B row stride (bf16): 80B rows, 16B-aligned, ~2-way read conflicts

__device__ __forceinline__ u16 f2bf(float f) {
  union { float f; unsigned u; } c; c.f = f;
  unsigned r = c.u + 0x7fffu + ((c.u >> 16) & 1u);   // RNE
  return (u16)(r >> 16);
}

__device__ __forceinline__ void gload_lds16(const void* g, void* l) {
  __builtin_amdgcn_global_load_lds(
      (const __attribute__((address_space(1))) unsigned int*)(uintptr_t)g,
      (__attribute__((address_space(3))) unsigned int*)(unsigned)(uintptr_t)l,
      16, 0, 0);
}

__global__ __launch_bounds__(64) void zero_k(int* counts) {
  if (threadIdx.x < NEXP) counts[threadIdx.x] = 0;
}

__global__ __launch_bounds__(64) void router_k(const float* __restrict__ x,
    const float* __restrict__ Wr, const float* __restrict__ br,
    int* __restrict__ counts, int* __restrict__ tok_exp, float* __restrict__ tok_gate) {
  const int t = blockIdx.x, l = threadIdx.x;
  const float* xr = x + (size_t)t * HD;
  float acc[NEXP];
#pragma unroll
  for (int j = 0; j < NEXP; ++j) acc[j] = 0.f;
  for (int h = l; h < HD; h += 64) {
    float xv = xr[h];
    const float4* w4 = (const float4*)(Wr + (size_t)h * NEXP);
    float4 a = w4[0], b = w4[1];
    acc[0] += xv * a.x; acc[1] += xv * a.y; acc[2] += xv * a.z; acc[3] += xv * a.w;
    acc[4] += xv * b.x; acc[5] += xv * b.y; acc[6] += xv * b.z; acc[7] += xv * b.w;
  }
#pragma unroll
  for (int j = 0; j < NEXP; ++j)
#pragma unroll
    for (int off = 32; off > 0; off >>= 1) acc[j] += __shfl_xor(acc[j], off);
  if (l == 0) {
    float lg[NEXP];
    float best = acc[0] + br[0]; int bi = 0;
    lg[0] = best;
#pragma unroll
    for (int j = 1; j < NEXP; ++j) {
      lg[j] = acc[j] + br[j];
      if (lg[j] > best) { best = lg[j]; bi = j; }
    }
    float s = 0.f;
#pragma unroll
    for (int j = 0; j < NEXP; ++j) s += expf(lg[j] - best);
    tok_exp[t] = bi;
    tok_gate[t] = 1.0f / s;
    atomicAdd(&counts[bi], 1);
  }
}

__global__ __launch_bounds__(64) void scan_k(const int* __restrict__ counts,
                                             int* __restrict__ seg, int* __restrict__ cursor) {
  if (threadIdx.x == 0) {
    int s = 0;
#pragma unroll
    for (int e = 0; e < NEXP; ++e) { seg[e] = s; cursor[e] = s; s += counts[e]; }
    seg[NEXP] = s;
  }
}

__global__ __launch_bounds__(64) void gather_k(const float* __restrict__ x,
    const int* __restrict__ tok_exp, const float* __restrict__ tok_gate,
    int* __restrict__ cursor, int* __restrict__ perm, float* __restrict__ gatep,
    u16* __restrict__ Xg) {
  const int t = blockIdx.x, l = threadIdx.x;
  int pos = 0;
  if (l == 0) {
    int e = tok_exp[t];
    pos = atomicAdd(&cursor[e], 1);
    perm[pos] = t;
    gatep[pos] = tok_gate[t];
  }
  pos = __shfl(pos, 0);
  const float4* xr = (const float4*)(x + (size_t)t * HD);
  ushort4* dst = (ushort4*)(Xg + (size_t)pos * HD);
#pragma unroll
  for (int i = 0; i < HD / 4 / 64; ++i) {
    float4 v = xr[l + i * 64];
    ushort4 o;
    o.x = f2bf(v.x); o.y = f2bf(v.y); o.z = f2bf(v.z); o.w = f2bf(v.w);
    dst[l + i * 64] = o;
  }
}

// Grouped GEMM, 2-phase double-buffered pipeline (T3 minimum + T14 reg-staged B).
// A: [T][KD] bf16 row-major (permuted). W: [E][KD][ND] f32.
// EPI 0: H1out = bf16(relu(acc+bias)).
// EPI 1: Yout[perm[row]] (+)= (acc [+bias if ks==0]) * gate  (atomic when KSPLIT>1)
template <int KD, int ND, int EPI, int KSPLIT>
__global__ __launch_bounds__(256) void ffn_gemm(
    const u16* __restrict__ A, const float* __restrict__ W,
    const float* __restrict__ bias, const int* __restrict__ seg,
    u16* __restrict__ H1out, float* __restrict__ Yout,
    const int* __restrict__ perm, const float* __restrict__ gatep) {
  const int e  = blockIdx.z & (NEXP - 1);
  const int ks = blockIdx.z >> 3;
  const int s0 = seg[e];
  const int cnt = seg[e + 1] - s0;
  const int m0 = blockIdx.y * BM;
  if (m0 >= cnt) return;
  const int n0 = blockIdx.x * BN;
  constexpr int KLEN = KD / KSPLIT;
  constexpr int NT = KLEN / BK;          // >= 2
  const int kbase = ks * KLEN;

  __shared__ __align__(16) u16 As[2][BM * BK];
  __shared__ __align__(16) u16 Bs[2][BN * BKP];

  const int t = threadIdx.x;
  const int l = t & 63, w = t >> 6;
  const int wr = w >> 1, wc = w & 1;

  const f32x4 fzero = {0.f, 0.f, 0.f, 0.f};
  f32x4 acc[4][4];
#pragma unroll
  for (int i = 0; i < 4; ++i)
#pragma unroll
    for (int j = 0; j < 4; ++j) acc[i][j] = fzero;

  // A staging: 2 chunks x 256 threads x 16B; chunk c -> row c>>2, k (c&3)*8, LDS slot c*16B
  const u16 *asrc0, *asrc1;
  {
    int row = t >> 2, kc = (t & 3) * 8;
    int rg = m0 + row; if (rg >= cnt) rg = cnt - 1;
    asrc0 = A + (size_t)(s0 + rg) * KD + kbase + kc;
    row = (256 + t) >> 2; kc = (t & 3) * 8;
    rg = m0 + row; if (rg >= cnt) rg = cnt - 1;
    asrc1 = A + (size_t)(s0 + rg) * KD + kbase + kc;
  }
  // B staging: thread covers 8k x 2n; coalesced 8B/lane loads, convert, 2x ds_write_b128
  const int nb = t & 63, kb = (t >> 6) * 8;
  const float* bp0 = W + (size_t)e * KD * ND + (size_t)(kbase + kb) * ND + n0 + nb * 2;

  float2 bv[8];

#define STAGE_A(buf, tt) do { \
    gload_lds16(asrc0 + (size_t)(tt) * BK, &As[buf][w * 512]); \
    gload_lds16(asrc1 + (size_t)(tt) * BK, &As[buf][2048 + w * 512]); \
  } while (0)

#define LOAD_B(tt) do { \
    const float* bp_ = bp0 + (size_t)(tt) * BK * ND; \
    _Pragma("unroll") for (int j_ = 0; j_ < 8; ++j_) bv[j_] = *(const float2*)(bp_ + (size_t)j_ * ND); \
  } while (0)

#define WRITE_B(buf) do { \
    s16x8 p0_, p1_; \
    _Pragma("unroll") for (int j_ = 0; j_ < 8; ++j_) { \
      p0_[j_] = (short)f2bf(bv[j_].x); p1_[j_] = (short)f2bf(bv[j_].y); } \
    *(s16x8*)&Bs[buf][(nb * 2 + 0) * BKP + kb] = p0_; \
    *(s16x8*)&Bs[buf][(nb * 2 + 1) * BKP + kb] = p1_; \
  } while (0)

#define COMPUTE(buf) do { \
    s16x8 af_[4], bf_[4]; \
    _Pragma("unroll") for (int mi_ = 0; mi_ < 4; ++mi_) \
      af_[mi_] = *(const s16x8*)&As[buf][(wr * 64 + mi_ * 16 + (l & 15)) * BK + (l >> 4) * 8]; \
    _Pragma("unroll") for (int ni_ = 0; ni_ < 4; ++ni_) \
      bf_[ni_] = *(const s16x8*)&Bs[buf][(wc * 64 + ni_ * 16 + (l & 15)) * BKP + (l >> 4) * 8]; \
    _Pragma("unroll") for (int mi_ = 0; mi_ < 4; ++mi_) \
      _Pragma("unroll") for (int ni_ = 0; ni_ < 4; ++ni_) \
        acc[mi_][ni_] = __builtin_amdgcn_mfma_f32_16x16x32_bf16(af_[mi_], bf_[ni_], acc[mi_][ni_], 0, 0, 0); \
  } while (0)

  // ---- prologue: tile 0 into buf 0; B(1) loads left in flight across the barrier
  STAGE_A(0, 0);
  LOAD_B(0);
  asm volatile("s_waitcnt vmcnt(0)" ::: "memory");
  __builtin_amdgcn_sched_barrier(0);
  WRITE_B(0);
  LOAD_B(1);
  asm volatile("s_waitcnt lgkmcnt(0)" ::: "memory");
  __builtin_amdgcn_s_barrier();
  __builtin_amdgcn_sched_barrier(0);

  // ---- main loop: compute(tt) overlaps A(tt+1) gload_lds + B(tt+2) reg loads
  for (int tt = 0; tt < NT - 1; ++tt) {
    const int cur = tt & 1, nxt = cur ^ 1;
    STAGE_A(nxt, tt + 1);               // async into free buffer (all waves past barrier)
    COMPUTE(cur);
    asm volatile("s_waitcnt vmcnt(0)" ::: "memory");   // A(tt+1) landed, B(tt+1) regs ready
    __builtin_amdgcn_sched_barrier(0);
    WRITE_B(nxt);
    if (tt + 2 < NT) LOAD_B(tt + 2);    // stays in flight across the barrier
    asm volatile("s_waitcnt lgkmcnt(0)" ::: "memory");
    __builtin_amdgcn_s_barrier();
    __builtin_amdgcn_sched_barrier(0);
  }
  COMPUTE((NT - 1) & 1);

#undef STAGE_A
#undef LOAD_B
#undef WRITE_B
#undef COMPUTE

  // epilogue: C/D frag map col=lane&15, row=(lane>>4)*4+reg  [m89/m91]
  const int lr = (l >> 4) * 4;
  const int lc = l & 15;
  float bv2[4];
#pragma unroll
  for (int ni = 0; ni < 4; ++ni)
    bv2[ni] = bias[(size_t)e * ND + n0 + wc * 64 + ni * 16 + lc];

  if constexpr (EPI == 0) {
#pragma unroll
    for (int mi = 0; mi < 4; ++mi) {
#pragma unroll
      for (int r = 0; r < 4; ++r) {
        int row = m0 + wr * 64 + mi * 16 + lr + r;
        if (row < cnt) {
          u16* hrow = H1out + (size_t)(s0 + row) * ND + n0 + wc * 64;
#pragma unroll
          for (int ni = 0; ni < 4; ++ni) {
            float v = acc[mi][ni][r] + bv2[ni];
            v = v > 0.f ? v : 0.f;
            hrow[ni * 16 + lc] = f2bf(v);
          }
        }
      }
    }
  } else {
#pragma unroll
    for (int mi = 0; mi < 4; ++mi) {
#pragma unroll
      for (int r = 0; r < 4; ++r) {
        int row = m0 + wr * 64 + mi * 16 + lr + r;
        if (row < cnt) {
          int tok = perm[s0 + row];
          float g = gatep[s0 + row];
          float* orow = Yout + (size_t)tok * ND + n0 + wc * 64;
#pragma unroll
          for (int ni = 0; ni < 4; ++ni) {
            float v = acc[mi][ni][r];
            if (KSPLIT == 1 || ks == 0) v += bv2[ni];
            v *= g;
            if constexpr (KSPLIT == 1) orow[ni * 16 + lc] = v;
            else atomicAdd(&orow[ni * 16 + lc], v);
          }
        }
      }
    }
  }
}

extern "C" void kernel_launch(void* const* d_in, const int* in_sizes, int n_in,
                              void* d_out, int out_size, void* d_ws, size_t ws_size,
                              hipStream_t stream) {
  const float* x  = (const float*)d_in[0];
  const float* Wr = (const float*)d_in[1];
  const float* br = (const float*)d_in[2];
  const float* W1 = (const float*)d_in[3];
  const float* b1 = (const float*)d_in[4];
  const float* W2 = (const float*)d_in[5];
  const float* b2 = (const float*)d_in[6];
  float* out = (float*)d_out;

  const int T = in_sizes[0] / HD;   // 4096 tokens
  char* ws = (char*)d_ws;
  int*   counts   = (int*)(ws + 0);
  int*   cursor   = (int*)(ws + 64);
  int*   seg      = (int*)(ws + 128);
  int*   tok_exp  = (int*)(ws + 256);
  float* tok_gate = (float*)(ws + 256 + 4 * (size_t)T);
  int*   perm     = (int*)(ws + 256 + 8 * (size_t)T);
  float* gatep    = (float*)(ws + 256 + 12 * (size_t)T);
  u16*   Xg       = (u16*)(ws + 256 + 16 * (size_t)T);                       // T*HD bf16
  u16*   H1       = (u16*)(ws + 256 + 16 * (size_t)T + 2 * (size_t)T * HD);  // T*DFF bf16

  hipMemsetAsync(out, 0, (size_t)out_size * sizeof(float), stream);  // split-K accumulates
  hipLaunchKernelGGL(zero_k, dim3(1), dim3(64), 0, stream, counts);
  hipLaunchKernelGGL(router_k, dim3(T), dim3(64), 0, stream, x, Wr, br, counts, tok_exp, tok_gate);
  hipLaunchKernelGGL(scan_k, dim3(1), dim3(64), 0, stream, counts, seg, cursor);
  hipLaunchKernelGGL(gather_k, dim3(T), dim3(64), 0, stream, x, tok_exp, tok_gate, cursor, perm, gatep, Xg);
  const int mt = (T + BM - 1) / BM;
  hipLaunchKernelGGL((ffn_gemm<HD, DFF, 0, 1>), dim3(DFF / BN, mt, NEXP), dim3(256), 0, stream,
                     Xg, W1, b1, seg, H1, nullptr, nullptr, nullptr);
  hipLaunchKernelGGL((ffn_gemm<DFF, HD, 1, 4>), dim3(HD / BN, mt, NEXP * 4), dim3(256), 0, stream,
                     H1, W2, b2, seg, nullptr, out, perm, gatep);
}

// Round 3
// 332.154 us; speedup vs baseline: 1.2355x; 1.0072x over previous
//
#include <hip/hip_runtime.h>
#include <stdint.h>

typedef unsigned short u16;
typedef __attribute__((ext_vector_type(8))) short s16x8;   // 8 bf16 in 4 VGPRs
typedef __attribute__((ext_vector_type(4))) float f32x4;   // MFMA accumulator
typedef __attribute__((ext_vector_type(4))) unsigned uint4v;

#define NEXP 8
#define HD 1024
#define DFF 4096
#define BM 128
#define BN 128
#define BK 32
// Bs image layout: [d=n&1][kbg=0..3][nb=0..63][8 u16]; kbg stride padded to 520 u16
#define BS_KSTR 520
#define BS_DSTR (4 * BS_KSTR)
#define BS_TOT  (2 * BS_DSTR)

__device__ __forceinline__ u16 f2bf(float f) {
  union { float f; unsigned u; } c; c.f = f;
  unsigned r = c.u + 0x7fffu + ((c.u >> 16) & 1u);   // RNE
  return (u16)(r >> 16);
}

__device__ __forceinline__ unsigned cvtpk(float a, float b) {
  unsigned r;
  asm("v_cvt_pk_bf16_f32 %0, %1, %2" : "=v"(r) : "v"(a), "v"(b));
  return r;   // lo = bf16(a), hi = bf16(b)
}

__device__ __forceinline__ void gload_lds16(const void* g, void* l) {
  __builtin_amdgcn_global_load_lds(
      (const __attribute__((address_space(1))) unsigned int*)(uintptr_t)g,
      (__attribute__((address_space(3))) unsigned int*)(unsigned)(uintptr_t)l,
      16, 0, 0);
}

__global__ __launch_bounds__(64) void zero_k(int* counts) {
  if (threadIdx.x < NEXP) counts[threadIdx.x] = 0;
}

__global__ __launch_bounds__(64) void router_k(const float* __restrict__ x,
    const float* __restrict__ Wr, const float* __restrict__ br,
    int* __restrict__ counts, int* __restrict__ tok_exp, float* __restrict__ tok_gate) {
  const int t = blockIdx.x, l = threadIdx.x;
  const float* xr = x + (size_t)t * HD;
  float acc[NEXP];
#pragma unroll
  for (int j = 0; j < NEXP; ++j) acc[j] = 0.f;
  for (int h = l; h < HD; h += 64) {
    float xv = xr[h];
    const float4* w4 = (const float4*)(Wr + (size_t)h * NEXP);
    float4 a = w4[0], b = w4[1];
    acc[0] += xv * a.x; acc[1] += xv * a.y; acc[2] += xv * a.z; acc[3] += xv * a.w;
    acc[4] += xv * b.x; acc[5] += xv * b.y; acc[6] += xv * b.z; acc[7] += xv * b.w;
  }
#pragma unroll
  for (int j = 0; j < NEXP; ++j)
#pragma unroll
    for (int off = 32; off > 0; off >>= 1) acc[j] += __shfl_xor(acc[j], off);
  if (l == 0) {
    float lg[NEXP];
    float best = acc[0] + br[0]; int bi = 0;
    lg[0] = best;
#pragma unroll
    for (int j = 1; j < NEXP; ++j) {
      lg[j] = acc[j] + br[j];
      if (lg[j] > best) { best = lg[j]; bi = j; }
    }
    float s = 0.f;
#pragma unroll
    for (int j = 0; j < NEXP; ++j) s += expf(lg[j] - best);
    tok_exp[t] = bi;
    tok_gate[t] = 1.0f / s;
    atomicAdd(&counts[bi], 1);
  }
}

__global__ __launch_bounds__(64) void scan_k(const int* __restrict__ counts,
                                             int* __restrict__ seg, int* __restrict__ cursor) {
  if (threadIdx.x == 0) {
    int s = 0;
#pragma unroll
    for (int e = 0; e < NEXP; ++e) { seg[e] = s; cursor[e] = s; s += counts[e]; }
    seg[NEXP] = s;
  }
}

__global__ __launch_bounds__(64) void gather_k(const float* __restrict__ x,
    const int* __restrict__ tok_exp, const float* __restrict__ tok_gate,
    int* __restrict__ cursor, int* __restrict__ perm, float* __restrict__ gatep,
    u16* __restrict__ Xg) {
  const int t = blockIdx.x, l = threadIdx.x;
  int pos = 0;
  if (l == 0) {
    int e = tok_exp[t];
    pos = atomicAdd(&cursor[e], 1);
    perm[pos] = t;
    gatep[pos] = tok_gate[t];
  }
  pos = __shfl(pos, 0);
  const float4* xr = (const float4*)(x + (size_t)t * HD);
  ushort4* dst = (ushort4*)(Xg + (size_t)pos * HD);
#pragma unroll
  for (int i = 0; i < HD / 4 / 64; ++i) {
    float4 v = xr[l + i * 64];
    ushort4 o;
    o.x = f2bf(v.x); o.y = f2bf(v.y); o.z = f2bf(v.z); o.w = f2bf(v.w);
    dst[l + i * 64] = o;
  }
}

// Grouped GEMM, depth-2 counted-vmcnt pipeline.
// A: [T][KD] bf16 (permuted rows). W: [E][KD][ND] f32 (converted on the fly via cvt_pk).
// EPI 0: H1out = bf16(relu(acc+bias)).
// EPI 1: Yout[perm[row]] (+)= (acc [+bias if ks==0]) * gate  (atomic when KSPLIT>1)
template <int KD, int ND, int EPI, int KSPLIT>
__global__ __launch_bounds__(256) void ffn_gemm(
    const u16* __restrict__ A, const float* __restrict__ W,
    const float* __restrict__ bias, const int* __restrict__ seg,
    u16* __restrict__ H1out, float* __restrict__ Yout,
    const int* __restrict__ perm, const float* __restrict__ gatep) {
  const int e  = blockIdx.z & (NEXP - 1);
  const int ks = blockIdx.z >> 3;
  const int s0 = seg[e];
  const int cnt = seg[e + 1] - s0;
  const int m0 = blockIdx.y * BM;
  if (m0 >= cnt) return;
  const int n0 = blockIdx.x * BN;
  constexpr int NT = (KD / KSPLIT) / BK;
  static_assert(NT >= 3, "pipeline needs >=3 K-tiles");
  const int kbase = ks * (KD / KSPLIT);

  __shared__ __align__(16) u16 As[3][BM * BK];   // 3 x 8KB, linear (gload_lds dest)
  __shared__ __align__(16) u16 Bs[2][BS_TOT];    // 2 x 8320B image layout

  const int t = threadIdx.x;
  const int l = t & 63, w = t >> 6;
  const int wr = w >> 1, wc = w & 1;

  const f32x4 fzero = {0.f, 0.f, 0.f, 0.f};
  f32x4 acc[4][4];
#pragma unroll
  for (int i = 0; i < 4; ++i)
#pragma unroll
    for (int j = 0; j < 4; ++j) acc[i][j] = fzero;

  // A staging: chunk c = i*4+w covers rows [c*16, c*16+16); lane l -> row c*16+(l>>2), k (l&3)*8
  const u16 *asrc0, *asrc1;
  {
    int row = w * 16 + (l >> 2), kc = (l & 3) * 8;
    int rg = m0 + row; if (rg >= cnt) rg = cnt - 1;
    asrc0 = A + (size_t)(s0 + rg) * KD + kbase + kc;
    row += 64;
    rg = m0 + row; if (rg >= cnt) rg = cnt - 1;
    asrc1 = A + (size_t)(s0 + rg) * KD + kbase + kc;
  }
  // B staging: thread covers rows {2nb, 2nb+1} x k [kbg*8, kbg*8+8)
  const int nb = t & 63, kbg = t >> 6;
  const float* bp0 = W + ((size_t)e * KD + kbase + kbg * 8) * ND + n0 + nb * 2;

  float2 bv[8];

#define STAGE_A(buf, tt) do { \
    gload_lds16(asrc0 + (size_t)(tt) * BK, &As[buf][w * 512]); \
    gload_lds16(asrc1 + (size_t)(tt) * BK, &As[buf][2048 + w * 512]); \
  } while (0)

#define LOAD_B(tt) do { \
    const float* bp_ = bp0 + (size_t)(tt) * BK * ND; \
    _Pragma("unroll") for (int j_ = 0; j_ < 8; ++j_) bv[j_] = *(const float2*)(bp_ + (size_t)j_ * ND); \
  } while (0)

#define WRITE_B(par) do { \
    uint4v q0_, q1_; \
    _Pragma("unroll") for (int j_ = 0; j_ < 4; ++j_) { \
      q0_[j_] = cvtpk(bv[2 * j_].x, bv[2 * j_ + 1].x); \
      q1_[j_] = cvtpk(bv[2 * j_].y, bv[2 * j_ + 1].y); } \
    *(uint4v*)&Bs[par][kbg * BS_KSTR + nb * 8] = q0_; \
    *(uint4v*)&Bs[par][BS_DSTR + kbg * BS_KSTR + nb * 8] = q1_; \
  } while (0)

#define COMPUTE(buf, par) do { \
    s16x8 af_[4], bf_[4]; \
    _Pragma("unroll") for (int mi_ = 0; mi_ < 4; ++mi_) \
      af_[mi_] = *(const s16x8*)&As[buf][(wr * 64 + mi_ * 16 + (l & 15)) * BK + (l >> 4) * 8]; \
    _Pragma("unroll") for (int ni_ = 0; ni_ < 4; ++ni_) { \
      int n_ = wc * 64 + ni_ * 16 + (l & 15); \
      bf_[ni_] = *(const s16x8*)&Bs[par][(n_ & 1) * BS_DSTR + (l >> 4) * BS_KSTR + (n_ >> 1) * 8]; \
    } \
    _Pragma("unroll") for (int mi_ = 0; mi_ < 4; ++mi_) \
      _Pragma("unroll") for (int ni_ = 0; ni_ < 4; ++ni_) \
        acc[mi_][ni_] = __builtin_amdgcn_mfma_f32_16x16x32_bf16(af_[mi_], bf_[ni_], acc[mi_][ni_], 0, 0, 0); \
  } while (0)

  // ---- prologue: B(0), A(0), A(1) issued; drain B(0)+A(0); A(1) stays in flight
  LOAD_B(0);
  __builtin_amdgcn_sched_barrier(0);
  STAGE_A(0, 0);
  STAGE_A(1, 1);
  asm volatile("s_waitcnt vmcnt(2)" ::: "memory");
  __builtin_amdgcn_sched_barrier(0);
  WRITE_B(0);
  asm volatile("s_waitcnt lgkmcnt(0)" ::: "memory");
  __builtin_amdgcn_s_barrier();
  __builtin_amdgcn_sched_barrier(0);

  // ---- steady state: B one tile ahead, A two tiles ahead; never drain to 0
  for (int tt = 0; tt < NT - 2; ++tt) {
    LOAD_B(tt + 1);
    __builtin_amdgcn_sched_barrier(0);
    STAGE_A((tt + 2) % 3, tt + 2);
    COMPUTE(tt % 3, tt & 1);
    asm volatile("s_waitcnt vmcnt(2)" ::: "memory");   // A(t+1),B(t+1) done; A(t+2) in flight
    __builtin_amdgcn_sched_barrier(0);
    WRITE_B((tt + 1) & 1);
    asm volatile("s_waitcnt lgkmcnt(0)" ::: "memory");
    __builtin_amdgcn_s_barrier();
    __builtin_amdgcn_sched_barrier(0);
  }
  // tt = NT-2: last B load, no more A stages
  LOAD_B(NT - 1);
  COMPUTE((NT - 2) % 3, (NT - 2) & 1);
  asm volatile("s_waitcnt vmcnt(0)" ::: "memory");
  __builtin_amdgcn_sched_barrier(0);
  WRITE_B((NT - 1) & 1);
  asm volatile("s_waitcnt lgkmcnt(0)" ::: "memory");
  __builtin_amdgcn_s_barrier();
  __builtin_amdgcn_sched_barrier(0);
  COMPUTE((NT - 1) % 3, (NT - 1) & 1);

#undef STAGE_A
#undef LOAD_B
#undef WRITE_B
#undef COMPUTE

  // epilogue: C/D frag map col=lane&15, row=(lane>>4)*4+reg  [m89/m91]
  const int lr = (l >> 4) * 4;
  const int lc = l & 15;
  float bv2[4];
#pragma unroll
  for (int ni = 0; ni < 4; ++ni)
    bv2[ni] = bias[(size_t)e * ND + n0 + wc * 64 + ni * 16 + lc];

  if constexpr (EPI == 0) {
#pragma unroll
    for (int mi = 0; mi < 4; ++mi) {
#pragma unroll
      for (int r = 0; r < 4; ++r) {
        int row = m0 + wr * 64 + mi * 16 + lr + r;
        if (row < cnt) {
          u16* hrow = H1out + (size_t)(s0 + row) * ND + n0 + wc * 64;
#pragma unroll
          for (int ni = 0; ni < 4; ++ni) {
            float v = acc[mi][ni][r] + bv2[ni];
            v = v > 0.f ? v : 0.f;
            hrow[ni * 16 + lc] = f2bf(v);
          }
        }
      }
    }
  } else {
#pragma unroll
    for (int mi = 0; mi < 4; ++mi) {
#pragma unroll
      for (int r = 0; r < 4; ++r) {
        int row = m0 + wr * 64 + mi * 16 + lr + r;
        if (row < cnt) {
          int tok = perm[s0 + row];
          float g = gatep[s0 + row];
          float* orow = Yout + (size_t)tok * ND + n0 + wc * 64;
#pragma unroll
          for (int ni = 0; ni < 4; ++ni) {
            float v = acc[mi][ni][r];
            if (KSPLIT == 1 || ks == 0) v += bv2[ni];
            v *= g;
            if constexpr (KSPLIT == 1) orow[ni * 16 + lc] = v;
            else atomicAdd(&orow[ni * 16 + lc], v);
          }
        }
      }
    }
  }
}

extern "C" void kernel_launch(void* const* d_in, const int* in_sizes, int n_in,
                              void* d_out, int out_size, void* d_ws, size_t ws_size,
                              hipStream_t stream) {
  const float* x  = (const float*)d_in[0];
  const float* Wr = (const float*)d_in[1];
  const float* br = (const float*)d_in[2];
  const float* W1 = (const float*)d_in[3];
  const float* b1 = (const float*)d_in[4];
  const float* W2 = (const float*)d_in[5];
  const float* b2 = (const float*)d_in[6];
  float* out = (float*)d_out;

  const int T = in_sizes[0] / HD;   // 4096 tokens
  char* ws = (char*)d_ws;
  int*   counts   = (int*)(ws + 0);
  int*   cursor   = (int*)(ws + 64);
  int*   seg      = (int*)(ws + 128);
  int*   tok_exp  = (int*)(ws + 256);
  float* tok_gate = (float*)(ws + 256 + 4 * (size_t)T);
  int*   perm     = (int*)(ws + 256 + 8 * (size_t)T);
  float* gatep    = (float*)(ws + 256 + 12 * (size_t)T);
  u16*   Xg       = (u16*)(ws + 256 + 16 * (size_t)T);                       // T*HD bf16
  u16*   H1       = (u16*)(ws + 256 + 16 * (size_t)T + 2 * (size_t)T * HD);  // T*DFF bf16

  hipMemsetAsync(out, 0, (size_t)out_size * sizeof(float), stream);  // split-K accumulates
  hipLaunchKernelGGL(zero_k, dim3(1), dim3(64), 0, stream, counts);
  hipLaunchKernelGGL(router_k, dim3(T), dim3(64), 0, stream, x, Wr, br, counts, tok_exp, tok_gate);
  hipLaunchKernelGGL(scan_k, dim3(1), dim3(64), 0, stream, counts, seg, cursor);
  hipLaunchKernelGGL(gather_k, dim3(T), dim3(64), 0, stream, x, tok_exp, tok_gate, cursor, perm, gatep, Xg);
  const int mt = (T + BM - 1) / BM;
  hipLaunchKernelGGL((ffn_gemm<HD, DFF, 0, 1>), dim3(DFF / BN, mt, NEXP), dim3(256), 0, stream,
                     Xg, W1, b1, seg, H1, nullptr, nullptr, nullptr);
  hipLaunchKernelGGL((ffn_gemm<DFF, HD, 1, 4>), dim3(HD / BN, mt, NEXP * 4), dim3(256), 0, stream,
                     H1, W2, b2, seg, nullptr, out, perm, gatep);
}